// Round 1
// baseline (190.514 us; speedup 1.0000x reference)
//
#include <hip/hip_runtime.h>

// MechanisticNRTLLoss — B=1e6 samples, scalar fp32 loss.
// One thread per sample. tau/G/tau*G hoisted (depend only on T,g) and reused
// across all 10 ln_gamma evaluations per sample. Block-reduce -> double
// atomicAdd into d_ws -> finalize kernel writes float d_out[0].

constexpr float ALPHA   = 0.3f;
constexpr float R_GAS   = 8.314462618f;
constexpr float EPS     = 1e-12f;
constexpr float TAU_CLIP= 10.0f;
constexpr float LN_CLIP = 20.0f;
constexpr float EPS_FD  = 1e-4f;
constexpr float LAM_PHY = 1.0f;
constexpr float LAM_GD  = 0.1f;
constexpr float LAM_TPD = 0.1f;

__device__ __forceinline__ float clipf(float v, float lo, float hi) {
    return fminf(fmaxf(v, lo), hi);
}

struct Mats {
    float tau[3][3];
    float G[3][3];
    float tG[3][3];   // tau * G
};

// ln_gamma for one composition x[3] given per-sample Mats.
// denom_i = max(sum_j x_j G[j][i], EPS); A_i = sum_j x_j (tau*G)[j][i]
// lg_i = A_i/denom_i + sum_j x_j G[i][j]/denom_j * (tau[i][j] - A_j/denom_j)
__device__ __forceinline__ void ln_gamma3(const float x[3], const Mats& M, float lg[3]) {
    float ratio[3], invd[3];
#pragma unroll
    for (int i = 0; i < 3; ++i) {
        float d = x[0] * M.G[0][i] + x[1] * M.G[1][i] + x[2] * M.G[2][i];
        d = fmaxf(d, EPS);
        float A = x[0] * M.tG[0][i] + x[1] * M.tG[1][i] + x[2] * M.tG[2][i];
        float inv = 1.0f / d;
        invd[i] = inv;
        ratio[i] = A * inv;
    }
#pragma unroll
    for (int i = 0; i < 3; ++i) {
        float s = ratio[i];
#pragma unroll
        for (int j = 0; j < 3; ++j) {
            s += x[j] * M.G[i][j] * invd[j] * (M.tau[i][j] - ratio[j]);
        }
        lg[i] = clipf(s, -LN_CLIP, LN_CLIP);
    }
}

__device__ __forceinline__ void renorm3(float x[3]) {
    x[0] = fmaxf(x[0], 0.0f);
    x[1] = fmaxf(x[1], 0.0f);
    x[2] = fmaxf(x[2], 0.0f);
    float inv = 1.0f / fmaxf(x[0] + x[1] + x[2], EPS);
    x[0] *= inv; x[1] *= inv; x[2] *= inv;
}

__global__ __launch_bounds__(256) void nrtl_loss_kernel(
    const float* __restrict__ pred,   // (B,6)
    const float* __restrict__ target, // (B,6)
    const float* __restrict__ Tarr,   // (B,)
    const float* __restrict__ g,      // (B,3,3)
    const float* __restrict__ dirs,   // (2,B,3)
    const float* __restrict__ noise,  // (4,B,3)
    double* __restrict__ acc, int B)
{
    const int i = blockIdx.x * blockDim.x + threadIdx.x;
    float contrib = 0.0f;

    if (i < B) {
        // ---- supervised MSE ----
        float sup = 0.0f;
        float p6[6];
#pragma unroll
        for (int k = 0; k < 6; ++k) {
            float pv = pred[i * 6 + k];
            float tv = target[i * 6 + k];
            float d  = pv - tv;
            sup += d * d;
            p6[k] = pv;
        }

        float xE[3] = {p6[0], p6[1], p6[2]};
        float xR[3] = {p6[3], p6[4], p6[5]};
        renorm3(xE);
        renorm3(xR);

        // ---- per-sample tau / G / tau*G (shared by all ln_gamma calls) ----
        const float Tc = fmaxf(Tarr[i], 1.0f);
        const float invRT = 1.0f / (R_GAS * Tc);
        Mats M;
#pragma unroll
        for (int a = 0; a < 3; ++a) {
#pragma unroll
            for (int b = 0; b < 3; ++b) {
                float ta = clipf(g[i * 9 + a * 3 + b] * invRT, -TAU_CLIP, TAU_CLIP);
                float Gv = expf(-ALPHA * ta);
                M.tau[a][b] = ta;
                M.G[a][b]   = Gv;
                M.tG[a][b]  = ta * Gv;
            }
        }

        float lgE[3], lgR[3];
        ln_gamma3(xE, M, lgE);
        ln_gamma3(xR, M, lgR);

        // ---- chemical-potential residual ----
        float logxE[3];
        float phy = 0.0f;
#pragma unroll
        for (int k = 0; k < 3; ++k) {
            logxE[k] = logf(fmaxf(xE[k], EPS));
            float r = logxE[k] + lgE[k] - logf(fmaxf(xR[k], EPS)) - lgR[k];
            phy += r * r;
        }

        // ---- Gibbs-Duhem FD penalty (2 directions) ----
        float gdsum = 0.0f;
#pragma unroll
        for (int d = 0; d < 2; ++d) {
            float dv[3];
#pragma unroll
            for (int k = 0; k < 3; ++k) dv[k] = dirs[(d * B + i) * 3 + k];
            float xp[3], xm[3];
#pragma unroll
            for (int k = 0; k < 3; ++k) {
                xp[k] = xE[k] + EPS_FD * dv[k];
                xm[k] = xE[k] - EPS_FD * dv[k];
            }
            renorm3(xp);
            renorm3(xm);
            float lgp[3], lgm[3];
            ln_gamma3(xp, M, lgp);
            ln_gamma3(xm, M, lgm);
            float gd = 0.0f;
            const float inv2e = 0.5f / EPS_FD;
#pragma unroll
            for (int k = 0; k < 3; ++k) gd += xE[k] * ((lgp[k] - lgm[k]) * inv2e);
            gdsum += gd * gd;
        }

        // ---- TPD penalty (4 trials) ----
        float tpdsum = 0.0f;
#pragma unroll
        for (int t = 0; t < 4; ++t) {
            float w[3];
#pragma unroll
            for (int k = 0; k < 3; ++k) w[k] = xE[k] + noise[(t * B + i) * 3 + k];
            renorm3(w);
            float lgw[3];
            ln_gamma3(w, M, lgw);
            float tpd = 0.0f;
#pragma unroll
            for (int k = 0; k < 3; ++k) {
                tpd += w[k] * (logf(fmaxf(w[k], EPS)) + lgw[k] - logxE[k] - lgE[k]);
            }
            tpdsum += fmaxf(-tpd, 0.0f);  // MARGIN = 0
        }

        const float invB = 1.0f / (float)B;
        contrib = invB * (sup * (1.0f / 6.0f)
                          + LAM_PHY * phy * (1.0f / 3.0f)
                          + LAM_GD  * gdsum * 0.5f
                          + LAM_TPD * tpdsum * 0.25f);
    }

    // ---- block reduction: wave shuffle then LDS across 4 waves ----
#pragma unroll
    for (int off = 32; off > 0; off >>= 1)
        contrib += __shfl_down(contrib, off, 64);

    __shared__ float ssum[4];
    const int lane = threadIdx.x & 63;
    const int wid  = threadIdx.x >> 6;
    if (lane == 0) ssum[wid] = contrib;
    __syncthreads();
    if (threadIdx.x == 0) {
        float bs = ssum[0] + ssum[1] + ssum[2] + ssum[3];
        atomicAdd(acc, (double)bs);
    }
}

__global__ void zero_ws_kernel(double* acc) { acc[0] = 0.0; }

__global__ void finalize_kernel(const double* acc, float* out) {
    out[0] = (float)acc[0];
}

extern "C" void kernel_launch(void* const* d_in, const int* in_sizes, int n_in,
                              void* d_out, int out_size, void* d_ws, size_t ws_size,
                              hipStream_t stream) {
    const float* pred   = (const float*)d_in[0];
    const float* target = (const float*)d_in[1];
    const float* Tarr   = (const float*)d_in[2];
    const float* g      = (const float*)d_in[3];
    const float* dirs   = (const float*)d_in[4];
    const float* noise  = (const float*)d_in[5];
    const int B = in_sizes[2];  // T is (B,)

    double* acc = (double*)d_ws;
    float*  out = (float*)d_out;

    zero_ws_kernel<<<1, 1, 0, stream>>>(acc);
    const int block = 256;
    const int grid  = (B + block - 1) / block;
    nrtl_loss_kernel<<<grid, block, 0, stream>>>(pred, target, Tarr, g, dirs, noise, acc, B);
    finalize_kernel<<<1, 1, 0, stream>>>(acc, out);
}

// Round 2
// 181.612 us; speedup vs baseline: 1.0490x; 1.0490x over previous
//
#include <hip/hip_runtime.h>

// MechanisticNRTLLoss — B=1e6 samples, scalar fp32 loss.
// R2: fast-math rewrite. All 1/x -> v_rcp_f32, expf/logf -> native v_exp/v_log.
// Per-block partial sums (no zero kernel, no atomics) + tiny reduce kernel.

constexpr float ALPHA    = 0.3f;
constexpr float R_GAS    = 8.314462618f;
constexpr float EPS      = 1e-12f;
constexpr float TAU_CLIP = 10.0f;
constexpr float LN_CLIP  = 20.0f;
constexpr float EPS_FD   = 1e-4f;
constexpr float LAM_PHY  = 1.0f;
constexpr float LAM_GD   = 0.1f;
constexpr float LAM_TPD  = 0.1f;

constexpr float LOG2E = 1.44269504088896340736f;
constexpr float LN2   = 0.69314718055994530942f;

__device__ __forceinline__ float clipf(float v, float lo, float hi) {
    return fminf(fmaxf(v, lo), hi);
}
// v_rcp_f32: ~1 ulp approx reciprocal — plenty for 2.7e-2 loss threshold
__device__ __forceinline__ float fast_rcp(float x) { return __builtin_amdgcn_rcpf(x); }
// native exp/log: 1 mul + v_exp_f32 / v_log_f32
__device__ __forceinline__ float fast_exp(float x) { return __expf(x); }
__device__ __forceinline__ float fast_log(float x) { return __logf(x); }

struct Mats {
    float tau[3][3];
    float G[3][3];
    float tG[3][3];   // tau * G
};

__device__ __forceinline__ void ln_gamma3(const float x[3], const Mats& M, float lg[3]) {
    float ratio[3], invd[3];
#pragma unroll
    for (int i = 0; i < 3; ++i) {
        float d = x[0] * M.G[0][i] + x[1] * M.G[1][i] + x[2] * M.G[2][i];
        d = fmaxf(d, EPS);
        float A = x[0] * M.tG[0][i] + x[1] * M.tG[1][i] + x[2] * M.tG[2][i];
        float inv = fast_rcp(d);
        invd[i] = inv;
        ratio[i] = A * inv;
    }
#pragma unroll
    for (int i = 0; i < 3; ++i) {
        float s = ratio[i];
#pragma unroll
        for (int j = 0; j < 3; ++j) {
            s += x[j] * M.G[i][j] * invd[j] * (M.tau[i][j] - ratio[j]);
        }
        lg[i] = clipf(s, -LN_CLIP, LN_CLIP);
    }
}

__device__ __forceinline__ void renorm3(float x[3]) {
    x[0] = fmaxf(x[0], 0.0f);
    x[1] = fmaxf(x[1], 0.0f);
    x[2] = fmaxf(x[2], 0.0f);
    float inv = fast_rcp(fmaxf(x[0] + x[1] + x[2], EPS));
    x[0] *= inv; x[1] *= inv; x[2] *= inv;
}

__global__ __launch_bounds__(256) void nrtl_loss_kernel(
    const float* __restrict__ pred,   // (B,6)
    const float* __restrict__ target, // (B,6)
    const float* __restrict__ Tarr,   // (B,)
    const float* __restrict__ g,      // (B,3,3)
    const float* __restrict__ dirs,   // (2,B,3)
    const float* __restrict__ noise,  // (4,B,3)
    float* __restrict__ partials, int B)
{
    const int i = blockIdx.x * blockDim.x + threadIdx.x;
    float contrib = 0.0f;

    if (i < B) {
        // ---- supervised MSE (rows are 8B-aligned: 6 floats = 24 B) ----
        const float2* p2 = (const float2*)(pred   + i * 6);
        const float2* t2 = (const float2*)(target + i * 6);
        float sup = 0.0f;
        float p6[6];
#pragma unroll
        for (int k = 0; k < 3; ++k) {
            float2 pv = p2[k];
            float2 tv = t2[k];
            float dx = pv.x - tv.x, dy = pv.y - tv.y;
            sup += dx * dx + dy * dy;
            p6[2 * k]     = pv.x;
            p6[2 * k + 1] = pv.y;
        }

        float xE[3] = {p6[0], p6[1], p6[2]};
        float xR[3] = {p6[3], p6[4], p6[5]};
        renorm3(xE);
        renorm3(xR);

        // ---- per-sample tau / G / tau*G ----
        const float Tc = fmaxf(Tarr[i], 1.0f);
        const float invRT = fast_rcp(R_GAS * Tc);
        Mats M;
#pragma unroll
        for (int a = 0; a < 3; ++a) {
#pragma unroll
            for (int b = 0; b < 3; ++b) {
                float ta = clipf(g[i * 9 + a * 3 + b] * invRT, -TAU_CLIP, TAU_CLIP);
                // exp(-alpha*tau) via exp2
                float Gv = __builtin_amdgcn_exp2f((-ALPHA * LOG2E) * ta);
                M.tau[a][b] = ta;
                M.G[a][b]   = Gv;
                M.tG[a][b]  = ta * Gv;
            }
        }

        float lgE[3], lgR[3];
        ln_gamma3(xE, M, lgE);
        ln_gamma3(xR, M, lgR);

        // ---- chemical-potential residual ----
        float logxE[3];
        float phy = 0.0f;
#pragma unroll
        for (int k = 0; k < 3; ++k) {
            logxE[k] = LN2 * __builtin_amdgcn_logf(fmaxf(xE[k], EPS));
            float logxR = LN2 * __builtin_amdgcn_logf(fmaxf(xR[k], EPS));
            float r = logxE[k] + lgE[k] - logxR - lgR[k];
            phy += r * r;
        }

        // ---- Gibbs-Duhem FD penalty (2 directions) ----
        float gdsum = 0.0f;
#pragma unroll
        for (int d = 0; d < 2; ++d) {
            float dv[3];
#pragma unroll
            for (int k = 0; k < 3; ++k) dv[k] = dirs[(d * B + i) * 3 + k];
            float xp[3], xm[3];
#pragma unroll
            for (int k = 0; k < 3; ++k) {
                xp[k] = xE[k] + EPS_FD * dv[k];
                xm[k] = xE[k] - EPS_FD * dv[k];
            }
            renorm3(xp);
            renorm3(xm);
            float lgp[3], lgm[3];
            ln_gamma3(xp, M, lgp);
            ln_gamma3(xm, M, lgm);
            float gd = 0.0f;
            const float inv2e = 0.5f / EPS_FD;
#pragma unroll
            for (int k = 0; k < 3; ++k) gd += xE[k] * ((lgp[k] - lgm[k]) * inv2e);
            gdsum += gd * gd;
        }

        // ---- TPD penalty (4 trials) ----
        float tpdsum = 0.0f;
#pragma unroll
        for (int t = 0; t < 4; ++t) {
            float w[3];
#pragma unroll
            for (int k = 0; k < 3; ++k) w[k] = xE[k] + noise[(t * B + i) * 3 + k];
            renorm3(w);
            float lgw[3];
            ln_gamma3(w, M, lgw);
            float tpd = 0.0f;
#pragma unroll
            for (int k = 0; k < 3; ++k) {
                float logw = LN2 * __builtin_amdgcn_logf(fmaxf(w[k], EPS));
                tpd += w[k] * (logw + lgw[k] - logxE[k] - lgE[k]);
            }
            tpdsum += fmaxf(-tpd, 0.0f);  // MARGIN = 0
        }

        const float invB = 1.0f / (float)B;
        contrib = invB * (sup * (1.0f / 6.0f)
                          + LAM_PHY * phy * (1.0f / 3.0f)
                          + LAM_GD  * gdsum * 0.5f
                          + LAM_TPD * tpdsum * 0.25f);
    }

    // ---- block reduction: wave shuffle then LDS across 4 waves ----
#pragma unroll
    for (int off = 32; off > 0; off >>= 1)
        contrib += __shfl_down(contrib, off, 64);

    __shared__ float ssum[4];
    const int lane = threadIdx.x & 63;
    const int wid  = threadIdx.x >> 6;
    if (lane == 0) ssum[wid] = contrib;
    __syncthreads();
    if (threadIdx.x == 0) {
        partials[blockIdx.x] = ssum[0] + ssum[1] + ssum[2] + ssum[3];
    }
}

// Reduce nblocks partials (every slot freshly written each launch; no init needed).
__global__ __launch_bounds__(256) void reduce_kernel(
    const float* __restrict__ partials, int n, float* __restrict__ out)
{
    double s = 0.0;
    for (int j = threadIdx.x; j < n; j += 256) s += (double)partials[j];
#pragma unroll
    for (int off = 32; off > 0; off >>= 1)
        s += __shfl_down(s, off, 64);
    __shared__ double ds[4];
    const int lane = threadIdx.x & 63;
    const int wid  = threadIdx.x >> 6;
    if (lane == 0) ds[wid] = s;
    __syncthreads();
    if (threadIdx.x == 0) out[0] = (float)(ds[0] + ds[1] + ds[2] + ds[3]);
}

extern "C" void kernel_launch(void* const* d_in, const int* in_sizes, int n_in,
                              void* d_out, int out_size, void* d_ws, size_t ws_size,
                              hipStream_t stream) {
    const float* pred   = (const float*)d_in[0];
    const float* target = (const float*)d_in[1];
    const float* Tarr   = (const float*)d_in[2];
    const float* g      = (const float*)d_in[3];
    const float* dirs   = (const float*)d_in[4];
    const float* noise  = (const float*)d_in[5];
    const int B = in_sizes[2];  // T is (B,)

    float* partials = (float*)d_ws;
    float* out      = (float*)d_out;

    const int block = 256;
    const int grid  = (B + block - 1) / block;
    nrtl_loss_kernel<<<grid, block, 0, stream>>>(pred, target, Tarr, g, dirs, noise, partials, B);
    reduce_kernel<<<1, block, 0, stream>>>(partials, grid, out);
}